// Round 2
// baseline (2065.614 us; speedup 1.0000x reference)
//
#include <hip/hip_runtime.h>

#define BB   256
#define NN   32
#define EMB  128
#define PEMB 64
#define ENCD 256
#define NLAY 4
#define W1C  261   // 2*EMB + 2*NCLS + 1
#define IND  193   // PEMB + 1 + EMB

// tanh(x) = 1 - 2/(exp(2x)+1); v_exp_f32 + v_rcp_f32, abs err ~1e-6, saturates correctly
__device__ __forceinline__ float fast_tanh(float x) {
  float e = __expf(2.0f * x);
  return 1.0f - __fdividef(2.0f, e + 1.0f);
}

__device__ __forceinline__ float dot16_lds(const float* base, const float* wreg) {
  const float4 a = *(const float4*)(base);
  const float4 b = *(const float4*)(base + 4);
  const float4 c = *(const float4*)(base + 8);
  const float4 d = *(const float4*)(base + 12);
  return a.x*wreg[0] + a.y*wreg[1] + a.z*wreg[2]  + a.w*wreg[3]
       + b.x*wreg[4] + b.y*wreg[5] + b.z*wreg[6]  + b.w*wreg[7]
       + c.x*wreg[8] + c.y*wreg[9] + c.z*wreg[10] + c.w*wreg[11]
       + d.x*wreg[12]+ d.y*wreg[13]+ d.z*wreg[14] + d.w*wreg[15];
}

__global__ __launch_bounds__(256, 1) void fsd_fused(
    const float* __restrict__ pos, const float* __restrict__ enc,
    const float* __restrict__ pos_emb, const float* __restrict__ na_emb,
    const int* __restrict__ T,
    const float* __restrict__ fc1_w, const float* __restrict__ fc1_b,
    const float* __restrict__ fc2_w, const float* __restrict__ fc2_b,
    const float* __restrict__ lin_w, const float* __restrict__ lin_b,
    const float* __restrict__ msg_w1, const float* __restrict__ msg_b1,
    const float* __restrict__ msg_w2, const float* __restrict__ msg_b2,
    const float* __restrict__ upd_w1, const float* __restrict__ upd_b1,
    const float* __restrict__ upd_w2, const float* __restrict__ upd_b2,
    float* __restrict__ out)
{
  __shared__ __align__(16) float h_s[NN][EMB];      // 16 KB
  __shared__ __align__(16) float u_s[NN][EMB];      // 16 KB (also pos_emb staging)
  __shared__ __align__(16) float v_s[NN][EMB];      // 16 KB
  __shared__ __align__(16) float aggr_s[NN][EMB];   // 16 KB
  __shared__ __align__(16) float2 w2p_s[EMB][64];   // 64 KB  w2p[k][j] = (W2[j][k], W2[j+64][k])  fp32
  __shared__ __align__(16) float ts_s[4][8][EMB];   // 16 KB  per-wave t tile (also hid for update MLP)
  __shared__ float e_s[EMB];
  __shared__ float c5_s[EMB];
  __shared__ float b2m_s[EMB];
  __shared__ float enc_s[ENCD];
  __shared__ float hidA_s[64];
  __shared__ float posx_s[NN], posy_s[NN];
  __shared__ int   T_s[NN];

  const int b    = blockIdx.x;
  const int tid  = threadIdx.x;
  const int w    = tid >> 6, lane = tid & 63;
  const int o    = tid & 127, g = tid >> 7;   // output index / node-group

  // ---------------- Phase A: decoder_fc -> e_s (per graph) ----------------
  enc_s[tid] = enc[b * ENCD + tid];
  if (tid < NN) {
    posx_s[tid] = pos[(b * NN + tid) * 2 + 0];
    posy_s[tid] = pos[(b * NN + tid) * 2 + 1];
    T_s[tid]    = T[b * NN + tid];
  }
  __syncthreads();
  if (tid < 64) {
    float a = fc1_b[tid];
    const float* wr = fc1_w + tid * ENCD;
    #pragma unroll 8
    for (int k = 0; k < ENCD; k++) a += enc_s[k] * wr[k];
    hidA_s[tid] = fast_tanh(a);
  }
  __syncthreads();
  if (tid < EMB) {
    float a = fc2_b[tid];
    const float* wr = fc2_w + tid * 64;
    #pragma unroll 8
    for (int k = 0; k < 64; k++) a += hidA_s[k] * wr[k];
    e_s[tid] = a;
  }
  // stage pos_emb into u_s area (free until layer loop)
  float* pe_s = &u_s[0][0];
  for (int idx = tid; idx < NN * PEMB; idx += 256)
    pe_s[idx] = pos_emb[b * NN * PEMB + idx];
  __syncthreads();

  // ---------------- Phase B: h0 = x @ lin_w^T + lin_b ----------------
  {
    const float nav = na_emb[b];
    const float* wr = lin_w + o * IND;
    float ebias = lin_b[o] + nav * wr[PEMB];
    #pragma unroll 8
    for (int k = 0; k < EMB; k++) ebias += e_s[k] * wr[65 + k];   // enc part: same for all nodes
    float acc[16];
    #pragma unroll
    for (int n = 0; n < 16; n++) acc[n] = ebias;
    for (int kc = 0; kc < PEMB; kc += 16) {
      float wreg[16];
      #pragma unroll
      for (int q = 0; q < 16; q++) wreg[q] = wr[kc + q];
      #pragma unroll
      for (int n = 0; n < 16; n++)
        acc[n] += dot16_lds(&pe_s[(g + 2 * n) * PEMB + kc], wreg);
    }
    __syncthreads();   // all pe_s reads done before u_s reuse in layer 0
    #pragma unroll
    for (int n = 0; n < 16; n++) h_s[g + 2 * n][o] = acc[n];
  }
  __syncthreads();

  // ---------------- Layer loop ----------------
  for (int l = 0; l < NLAY; l++) {
    const float* w1  = msg_w1 + l * EMB * W1C;
    const float* b1  = msg_b1 + l * EMB;
    const float* w2  = msg_w2 + l * EMB * EMB;
    const float* b2  = msg_b2 + l * EMB;
    const float* uw1 = upd_w1 + l * EMB * 2 * EMB;
    const float* ub1 = upd_b1 + l * EMB;
    const float* uw2 = upd_w2 + l * EMB * EMB;
    const float* ub2 = upd_b2 + l * EMB;

    // ---- stage W2 (fp32, transposed, paired), dist column, msg bias ----
    for (int idx = tid; idx < EMB * 64; idx += 256) {
      const int k = idx >> 6, j = idx & 63;
      w2p_s[k][j] = make_float2(w2[j * EMB + k], w2[(j + 64) * EMB + k]);
    }
    if (tid < EMB) { c5_s[tid] = w1[tid * W1C + 260]; b2m_s[tid] = b2[tid]; }

    // ---- Phase C: per-node u,v (decomposed first msg layer) ----
    {
      const float* wr = w1 + o * W1C;
      const float b1o = b1[o];
      float accU[16], accV[16];
      #pragma unroll
      for (int n = 0; n < 16; n++) {
        const int node = g + 2 * n;
        const int cls  = T_s[node];
        accU[n] = b1o + wr[258 + cls];   // dst one-hot cols + bias
        accV[n] = wr[256 + cls];         // src one-hot cols
      }
      for (int kc = 0; kc < EMB; kc += 16) {
        float wu[16], wv[16];
        #pragma unroll
        for (int q = 0; q < 16; q++) { wu[q] = wr[kc + q]; wv[q] = wr[EMB + kc + q]; }
        #pragma unroll
        for (int n = 0; n < 16; n++) {
          const int node = g + 2 * n;
          const float4 a0 = *(const float4*)&h_s[node][kc];
          const float4 a1 = *(const float4*)&h_s[node][kc + 4];
          const float4 a2 = *(const float4*)&h_s[node][kc + 8];
          const float4 a3 = *(const float4*)&h_s[node][kc + 12];
          float su = a0.x*wu[0] + a0.y*wu[1] + a0.z*wu[2]  + a0.w*wu[3]
                   + a1.x*wu[4] + a1.y*wu[5] + a1.z*wu[6]  + a1.w*wu[7]
                   + a2.x*wu[8] + a2.y*wu[9] + a2.z*wu[10] + a2.w*wu[11]
                   + a3.x*wu[12]+ a3.y*wu[13]+ a3.z*wu[14] + a3.w*wu[15];
          float sv = a0.x*wv[0] + a0.y*wv[1] + a0.z*wv[2]  + a0.w*wv[3]
                   + a1.x*wv[4] + a1.y*wv[5] + a1.z*wv[6]  + a1.w*wv[7]
                   + a2.x*wv[8] + a2.y*wv[9] + a2.z*wv[10] + a2.w*wv[11]
                   + a3.x*wv[12]+ a3.y*wv[13]+ a3.z*wv[14] + a3.w*wv[15];
          accU[n] += su; accV[n] += sv;
        }
      }
      #pragma unroll
      for (int n = 0; n < 16; n++) {
        const int node = g + 2 * n;
        u_s[node][o] = accU[n]; v_s[node][o] = accV[n];
      }
    }
    __syncthreads();

    // ---- Phase D: edges. wave w owns dst nodes i = w, w+4, ... ----
    {
      float (*ts)[EMB] = ts_s[w];
      const float c50 = c5_s[lane], c51 = c5_s[lane + 64];
      const float bb0 = b2m_s[lane], bb1 = b2m_s[lane + 64];
      for (int i = w; i < NN; i += 4) {
        const float u0 = u_s[i][lane], u1 = u_s[i][lane + 64];
        const float pix = posx_s[i], piy = posy_s[i];
        float agg0 = 0.f, agg1 = 0.f;
        for (int jc = 0; jc < NN; jc += 8) {
          #pragma unroll
          for (int jj = 0; jj < 8; jj++) {
            const int j = jc + jj;
            const float dx = posx_s[j] - pix, dy = posy_s[j] - piy;
            const float d = sqrtf(dx * dx + dy * dy);
            ts[jj][lane]      = fast_tanh(u0 + v_s[j][lane]      + d * c50);
            ts[jj][lane + 64] = fast_tanh(u1 + v_s[j][lane + 64] + d * c51);
          }
          __syncthreads();   // fence for cross-lane ts visibility (uniform trip counts)
          float acc[8][2];
          #pragma unroll
          for (int jj = 0; jj < 8; jj++) { acc[jj][0] = 0.f; acc[jj][1] = 0.f; }
          #pragma unroll 4
          for (int k4 = 0; k4 < EMB; k4 += 4) {
            const float2 wq0 = w2p_s[k4 + 0][lane];
            const float2 wq1 = w2p_s[k4 + 1][lane];
            const float2 wq2 = w2p_s[k4 + 2][lane];
            const float2 wq3 = w2p_s[k4 + 3][lane];
            #pragma unroll
            for (int jj = 0; jj < 8; jj++) {
              const float4 tv = *(const float4*)&ts[jj][k4];
              acc[jj][0] += tv.x*wq0.x + tv.y*wq1.x + tv.z*wq2.x + tv.w*wq3.x;
              acc[jj][1] += tv.x*wq0.y + tv.y*wq1.y + tv.z*wq2.y + tv.w*wq3.y;
            }
          }
          #pragma unroll
          for (int jj = 0; jj < 8; jj++) {
            agg0 += fast_tanh(acc[jj][0] + bb0);
            agg1 += fast_tanh(acc[jj][1] + bb1);
          }
          __syncthreads();
        }
        aggr_s[i][lane]      = agg0;
        aggr_s[i][lane + 64] = agg1;
      }
    }
    __syncthreads();

    // ---- Phase E: update MLP + residual ----
    float* hid = &ts_s[0][0][0];   // 32*128 floats, reuse ts space
    {
      const float* wr = uw1 + o * (2 * EMB);
      const float bo = ub1[o];
      float acc[16];
      #pragma unroll
      for (int n = 0; n < 16; n++) acc[n] = bo;
      for (int kc = 0; kc < EMB; kc += 16) {
        float wa[16], wb[16];
        #pragma unroll
        for (int q = 0; q < 16; q++) { wa[q] = wr[kc + q]; wb[q] = wr[EMB + kc + q]; }
        #pragma unroll
        for (int n = 0; n < 16; n++) {
          const int node = g + 2 * n;
          acc[n] += dot16_lds(&h_s[node][kc], wa) + dot16_lds(&aggr_s[node][kc], wb);
        }
      }
      #pragma unroll
      for (int n = 0; n < 16; n++) hid[(g + 2 * n) * EMB + o] = fast_tanh(acc[n]);
    }
    __syncthreads();
    {
      const float* wr = uw2 + o * EMB;
      const float bo = ub2[o];
      float acc[16];
      #pragma unroll
      for (int n = 0; n < 16; n++) acc[n] = bo;
      for (int kc = 0; kc < EMB; kc += 16) {
        float wa[16];
        #pragma unroll
        for (int q = 0; q < 16; q++) wa[q] = wr[kc + q];
        #pragma unroll
        for (int n = 0; n < 16; n++)
          acc[n] += dot16_lds(&hid[(g + 2 * n) * EMB + kc], wa);
      }
      #pragma unroll
      for (int n = 0; n < 16; n++) h_s[g + 2 * n][o] += fast_tanh(acc[n]);
    }
    __syncthreads();
  }

  // ---------------- write out ----------------
  {
    const float* hf = &h_s[0][0];
    for (int idx = tid; idx < NN * EMB; idx += 256)
      out[b * NN * EMB + idx] = hf[idx];
  }
}

extern "C" void kernel_launch(void* const* d_in, const int* in_sizes, int n_in,
                              void* d_out, int out_size, void* d_ws, size_t ws_size,
                              hipStream_t stream) {
  const float* pos     = (const float*)d_in[0];
  const float* enc     = (const float*)d_in[1];
  const float* pos_emb = (const float*)d_in[2];
  const float* na_emb  = (const float*)d_in[3];
  const int*   T       = (const int*)d_in[4];
  // d_in[5] = num_agents (compile-time 32)
  const float* fc1_w = (const float*)d_in[6];
  const float* fc1_b = (const float*)d_in[7];
  const float* fc2_w = (const float*)d_in[8];
  const float* fc2_b = (const float*)d_in[9];
  const float* lin_w = (const float*)d_in[10];
  const float* lin_b = (const float*)d_in[11];
  const float* msg_w1 = (const float*)d_in[12];
  const float* msg_b1 = (const float*)d_in[13];
  const float* msg_w2 = (const float*)d_in[14];
  const float* msg_b2 = (const float*)d_in[15];
  const float* upd_w1 = (const float*)d_in[16];
  const float* upd_b1 = (const float*)d_in[17];
  const float* upd_w2 = (const float*)d_in[18];
  const float* upd_b2 = (const float*)d_in[19];

  fsd_fused<<<BB, 256, 0, stream>>>(pos, enc, pos_emb, na_emb, T,
      fc1_w, fc1_b, fc2_w, fc2_b, lin_w, lin_b,
      msg_w1, msg_b1, msg_w2, msg_b2, upd_w1, upd_b1, upd_w2, upd_b2,
      (float*)d_out);
}

// Round 3
// 408.036 us; speedup vs baseline: 5.0623x; 5.0623x over previous
//
#include <hip/hip_runtime.h>

#define NN   32
#define EMB  128
#define PEMB 64
#define ENCD 256
#define NLAY 4
#define W1C  261   // 2*EMB + 2*NCLS + 1
#define IND  193   // PEMB + 1 + EMB
#define UPAD 132   // padded row (floats) for u_s/v_s: +16B breaks bank pattern

typedef __attribute__((ext_vector_type(8))) short short8;
typedef __attribute__((ext_vector_type(4))) float floatx4;

// tanh(x) = 1 - 2/(exp(2x)+1); v_exp_f32 + v_rcp_f32, abs err ~1e-6
__device__ __forceinline__ float fast_tanh(float x) {
  float e = __expf(2.0f * x);
  return 1.0f - __fdividef(2.0f, e + 1.0f);
}
// fp32 -> bf16 RNE
__device__ __forceinline__ unsigned short f2bf(float x) {
  unsigned u = __float_as_uint(x);
  return (unsigned short)((u + 0x7fffu + ((u >> 16) & 1u)) >> 16);
}
__device__ __forceinline__ float bf2f(unsigned short h) {
  return __uint_as_float(((unsigned)h) << 16);
}

__device__ __forceinline__ float dot16_lds(const float* base, const float* wreg) {
  const float4 a = *(const float4*)(base);
  const float4 b = *(const float4*)(base + 4);
  const float4 c = *(const float4*)(base + 8);
  const float4 d = *(const float4*)(base + 12);
  return a.x*wreg[0] + a.y*wreg[1] + a.z*wreg[2]  + a.w*wreg[3]
       + b.x*wreg[4] + b.y*wreg[5] + b.z*wreg[6]  + b.w*wreg[7]
       + c.x*wreg[8] + c.y*wreg[9] + c.z*wreg[10] + c.w*wreg[11]
       + d.x*wreg[12]+ d.y*wreg[13]+ d.z*wreg[14] + d.w*wreg[15];
}

__global__ __launch_bounds__(512, 1) void fsd_fused(
    const float* __restrict__ pos, const float* __restrict__ enc,
    const float* __restrict__ pos_emb, const float* __restrict__ na_emb,
    const int* __restrict__ T,
    const float* __restrict__ fc1_w, const float* __restrict__ fc1_b,
    const float* __restrict__ fc2_w, const float* __restrict__ fc2_b,
    const float* __restrict__ lin_w, const float* __restrict__ lin_b,
    const float* __restrict__ msg_w1, const float* __restrict__ msg_b1,
    const float* __restrict__ msg_w2, const float* __restrict__ msg_b2,
    const float* __restrict__ upd_w1, const float* __restrict__ upd_b1,
    const float* __restrict__ upd_w2, const float* __restrict__ upd_b2,
    float* __restrict__ out)
{
  __shared__ __align__(16) float h_s[NN][EMB];        // 16 KB (broadcast reads only)
  __shared__ __align__(16) float u_s[NN][UPAD];       // 16.9 KB (padded)
  __shared__ __align__(16) float v_s[NN][UPAD];       // 16.9 KB (padded)
  __shared__ __align__(16) float aggr_s[NN][EMB];     // 16 KB
  __shared__ __align__(16) unsigned short aT[2][2][4][64][8]; // 16 KB: [buf][jt][kt][fraglane][m]
  __shared__ float e_s[EMB];
  __shared__ float c5_s[EMB];
  __shared__ float enc_s[ENCD];
  __shared__ float hidA_s[64];
  __shared__ float posx_s[NN], posy_s[NN];
  __shared__ int   T_s[NN];

  const int b    = blockIdx.x;
  const int tid  = threadIdx.x;
  const int w    = tid >> 6, lane = tid & 63;   // 8 waves
  const int o    = tid & 127, g = tid >> 7;     // g in [0,4): node-group for node phases
  const int koct = tid & 15, jn = tid >> 4;     // t-compute mapping: k-octet, source node j
  const int k0   = koct << 3;

  // ---------------- Phase A: decoder_fc -> e_s ----------------
  if (tid < ENCD) enc_s[tid] = enc[b * ENCD + tid];
  if (tid < NN) {
    posx_s[tid] = pos[(b * NN + tid) * 2 + 0];
    posy_s[tid] = pos[(b * NN + tid) * 2 + 1];
    T_s[tid]    = T[b * NN + tid];
  }
  __syncthreads();
  if (tid < 64) {
    float a = fc1_b[tid];
    const float* wr = fc1_w + tid * ENCD;
    #pragma unroll 8
    for (int k = 0; k < ENCD; k++) a += enc_s[k] * wr[k];
    hidA_s[tid] = fast_tanh(a);
  }
  __syncthreads();
  if (tid < EMB) {
    float a = fc2_b[tid];
    const float* wr = fc2_w + tid * 64;
    #pragma unroll 8
    for (int k = 0; k < 64; k++) a += hidA_s[k] * wr[k];
    e_s[tid] = a;
  }
  // stage pos_emb into u_s region (free until Phase C of layer 0)
  float* pe_s = &u_s[0][0];
  for (int idx = tid; idx < NN * PEMB; idx += 512)
    pe_s[idx] = pos_emb[b * NN * PEMB + idx];
  __syncthreads();

  // ---------------- Phase B: h0 = x @ lin_w^T + lin_b ----------------
  {
    const float nav = na_emb[b];
    const float* wr = lin_w + o * IND;
    float ebias = lin_b[o] + nav * wr[PEMB];
    #pragma unroll 8
    for (int k = 0; k < EMB; k++) ebias += e_s[k] * wr[65 + k];
    float acc[8];
    #pragma unroll
    for (int n = 0; n < 8; n++) acc[n] = ebias;
    for (int kc = 0; kc < PEMB; kc += 16) {
      float wreg[16];
      #pragma unroll
      for (int q = 0; q < 16; q++) wreg[q] = wr[kc + q];
      #pragma unroll
      for (int n = 0; n < 8; n++)
        acc[n] += dot16_lds(&pe_s[(g + 4 * n) * PEMB + kc], wreg);
    }
    #pragma unroll
    for (int n = 0; n < 8; n++) h_s[g + 4 * n][o] = acc[n];
  }
  __syncthreads();

  // ---------------- Layer loop ----------------
  for (int l = 0; l < NLAY; l++) {
    const float* w1  = msg_w1 + l * EMB * W1C;
    const float* b1  = msg_b1 + l * EMB;
    const float* w2  = msg_w2 + l * EMB * EMB;
    const float* b2  = msg_b2 + l * EMB;
    const float* uw1 = upd_w1 + l * EMB * 2 * EMB;
    const float* ub1 = upd_b1 + l * EMB;
    const float* uw2 = upd_w2 + l * EMB * EMB;
    const float* ub2 = upd_b2 + l * EMB;

    if (tid < EMB) c5_s[tid] = w1[tid * W1C + 260];   // dist column

    // ---- Phase C: per-node u,v (decomposed first msg layer), fp32 VALU ----
    {
      const float* wr = w1 + o * W1C;
      const float b1o = b1[o];
      float accU[8], accV[8];
      #pragma unroll
      for (int n = 0; n < 8; n++) {
        const int node = g + 4 * n;
        const int cls  = T_s[node];
        accU[n] = b1o + wr[258 + cls];   // dst one-hot + bias
        accV[n] = wr[256 + cls];         // src one-hot
      }
      for (int kc = 0; kc < EMB; kc += 16) {
        float wu[16], wv[16];
        #pragma unroll
        for (int q = 0; q < 16; q++) { wu[q] = wr[kc + q]; wv[q] = wr[EMB + kc + q]; }
        #pragma unroll
        for (int n = 0; n < 8; n++) {
          const int node = g + 4 * n;
          const float4 a0 = *(const float4*)&h_s[node][kc];
          const float4 a1 = *(const float4*)&h_s[node][kc + 4];
          const float4 a2 = *(const float4*)&h_s[node][kc + 8];
          const float4 a3 = *(const float4*)&h_s[node][kc + 12];
          accU[n] += a0.x*wu[0] + a0.y*wu[1] + a0.z*wu[2]  + a0.w*wu[3]
                   + a1.x*wu[4] + a1.y*wu[5] + a1.z*wu[6]  + a1.w*wu[7]
                   + a2.x*wu[8] + a2.y*wu[9] + a2.z*wu[10] + a2.w*wu[11]
                   + a3.x*wu[12]+ a3.y*wu[13]+ a3.z*wu[14] + a3.w*wu[15];
          accV[n] += a0.x*wv[0] + a0.y*wv[1] + a0.z*wv[2]  + a0.w*wv[3]
                   + a1.x*wv[4] + a1.y*wv[5] + a1.z*wv[6]  + a1.w*wv[7]
                   + a2.x*wv[8] + a2.y*wv[9] + a2.z*wv[10] + a2.w*wv[11]
                   + a3.x*wv[12]+ a3.y*wv[13]+ a3.z*wv[14] + a3.w*wv[15];
        }
      }
      #pragma unroll
      for (int n = 0; n < 8; n++) {
        const int node = g + 4 * n;
        u_s[node][o] = accU[n]; v_s[node][o] = accV[n];
      }
    }
    __syncthreads();

    // ---- Phase D prologue: W2 hi/lo B-fragments into REGISTERS (wave w owns outs [16w,16w+16)) ----
    short8 whi[4], wlo[4];
    {
      const int orow = (w << 4) + (lane & 15);
      const float* wbase = w2 + orow * EMB + ((lane >> 4) << 3);
      #pragma unroll
      for (int kt = 0; kt < 4; kt++) {
        float wv8[8];
        *(float4*)&wv8[0] = *(const float4*)(wbase + kt * 32);
        *(float4*)&wv8[4] = *(const float4*)(wbase + kt * 32 + 4);
        #pragma unroll
        for (int m = 0; m < 8; m++) {
          const unsigned short h = f2bf(wv8[m]);
          whi[kt][m] = (short)h;
          wlo[kt][m] = (short)f2bf(wv8[m] - bf2f(h));
        }
      }
    }
    const float b2r = b2[(w << 4) + (lane & 15)];
    float c5v[8];
    *(float4*)&c5v[0] = *(const float4*)&c5_s[k0];
    *(float4*)&c5v[4] = *(const float4*)&c5_s[k0 + 4];

    // ---- Phase D: per dst-node i: build t (bf16 A-frags), MFMA, reduce over j ----
    const int jt_w  = jn >> 4;
    const int kt_w  = koct >> 2;
    const int slot  = (jn & 15) + ((koct & 3) << 4);
    for (int i = 0; i < NN; i++) {
      const int buf = i & 1;
      // t[jn][k0..k0+8) = tanh(u_i + v_jn + d*c5), packed bf16 into A-frag slot
      float uv[8], vv[8];
      *(float4*)&uv[0] = *(const float4*)&u_s[i][k0];
      *(float4*)&uv[4] = *(const float4*)&u_s[i][k0 + 4];
      *(float4*)&vv[0] = *(const float4*)&v_s[jn][k0];
      *(float4*)&vv[4] = *(const float4*)&v_s[jn][k0 + 4];
      const float dx = posx_s[jn] - posx_s[i], dy = posy_s[jn] - posy_s[i];
      const float d  = sqrtf(dx * dx + dy * dy);
      short8 tpk;
      #pragma unroll
      for (int m = 0; m < 8; m++)
        tpk[m] = (short)f2bf(fast_tanh(uv[m] + vv[m] + d * c5v[m]));
      *(short8*)&aT[buf][jt_w][kt_w][slot][0] = tpk;
      __syncthreads();   // aT[buf] complete; also fences reads of aT[buf] from iter i-2

      // MFMA: D[j][o] += t[j][k] * W2[o][k]  (A=t frag, B=W2^T frag hi+lo)
      floatx4 a0 = {0.f, 0.f, 0.f, 0.f};
      floatx4 a1 = {0.f, 0.f, 0.f, 0.f};
      #pragma unroll
      for (int kt = 0; kt < 4; kt++) {
        const short8 f0 = *(const short8*)&aT[buf][0][kt][lane][0];
        const short8 f1 = *(const short8*)&aT[buf][1][kt][lane][0];
        a0 = __builtin_amdgcn_mfma_f32_16x16x32_bf16(f0, wlo[kt], a0, 0, 0, 0);
        a0 = __builtin_amdgcn_mfma_f32_16x16x32_bf16(f0, whi[kt], a0, 0, 0, 0);
        a1 = __builtin_amdgcn_mfma_f32_16x16x32_bf16(f1, wlo[kt], a1, 0, 0, 0);
        a1 = __builtin_amdgcn_mfma_f32_16x16x32_bf16(f1, whi[kt], a1, 0, 0, 0);
      }
      // epilogue: m = tanh(C + b2), aggregate over j (rows): regs + xor-shuffles
      float p = 0.f;
      #pragma unroll
      for (int q = 0; q < 4; q++)
        p += fast_tanh(a0[q] + b2r) + fast_tanh(a1[q] + b2r);
      p += __shfl_xor(p, 16);
      p += __shfl_xor(p, 32);
      if (lane < 16) aggr_s[i][(w << 4) + lane] = p;
    }
    __syncthreads();

    // ---- Phase E: update MLP + residual (fp32 VALU) ----
    float* hid = (float*)&aT[0][0][0][0][0];   // 4096 floats, reuse aT space
    {
      const float* wr = uw1 + o * (2 * EMB);
      const float bo = ub1[o];
      float acc[8];
      #pragma unroll
      for (int n = 0; n < 8; n++) acc[n] = bo;
      for (int kc = 0; kc < EMB; kc += 16) {
        float wa[16], wb[16];
        #pragma unroll
        for (int q = 0; q < 16; q++) { wa[q] = wr[kc + q]; wb[q] = wr[EMB + kc + q]; }
        #pragma unroll
        for (int n = 0; n < 8; n++) {
          const int node = g + 4 * n;
          acc[n] += dot16_lds(&h_s[node][kc], wa) + dot16_lds(&aggr_s[node][kc], wb);
        }
      }
      #pragma unroll
      for (int n = 0; n < 8; n++) hid[(g + 4 * n) * EMB + o] = fast_tanh(acc[n]);
    }
    __syncthreads();
    {
      const float* wr = uw2 + o * EMB;
      const float bo = ub2[o];
      float acc[8];
      #pragma unroll
      for (int n = 0; n < 8; n++) acc[n] = bo;
      for (int kc = 0; kc < EMB; kc += 16) {
        float wa[16];
        #pragma unroll
        for (int q = 0; q < 16; q++) wa[q] = wr[kc + q];
        #pragma unroll
        for (int n = 0; n < 8; n++)
          acc[n] += dot16_lds(&hid[(g + 4 * n) * EMB + kc], wa);
      }
      #pragma unroll
      for (int n = 0; n < 8; n++) h_s[g + 4 * n][o] += fast_tanh(acc[n]);
    }
    __syncthreads();
  }

  // ---------------- write out ----------------
  {
    const float* hf = &h_s[0][0];
    for (int idx = tid; idx < NN * EMB; idx += 512)
      out[b * NN * EMB + idx] = hf[idx];
  }
}

extern "C" void kernel_launch(void* const* d_in, const int* in_sizes, int n_in,
                              void* d_out, int out_size, void* d_ws, size_t ws_size,
                              hipStream_t stream) {
  const float* pos     = (const float*)d_in[0];
  const float* enc     = (const float*)d_in[1];
  const float* pos_emb = (const float*)d_in[2];
  const float* na_emb  = (const float*)d_in[3];
  const int*   T       = (const int*)d_in[4];
  // d_in[5] = num_agents (compile-time 32)
  const float* fc1_w = (const float*)d_in[6];
  const float* fc1_b = (const float*)d_in[7];
  const float* fc2_w = (const float*)d_in[8];
  const float* fc2_b = (const float*)d_in[9];
  const float* lin_w = (const float*)d_in[10];
  const float* lin_b = (const float*)d_in[11];
  const float* msg_w1 = (const float*)d_in[12];
  const float* msg_b1 = (const float*)d_in[13];
  const float* msg_w2 = (const float*)d_in[14];
  const float* msg_b2 = (const float*)d_in[15];
  const float* upd_w1 = (const float*)d_in[16];
  const float* upd_b1 = (const float*)d_in[17];
  const float* upd_w2 = (const float*)d_in[18];
  const float* upd_b2 = (const float*)d_in[19];

  fsd_fused<<<256, 512, 0, stream>>>(pos, enc, pos_emb, na_emb, T,
      fc1_w, fc1_b, fc2_w, fc2_b, lin_w, lin_b,
      msg_w1, msg_b1, msg_w2, msg_b2, upd_w1, upd_b1, upd_w2, upd_b2,
      (float*)d_out);
}

// Round 4
// 285.378 us; speedup vs baseline: 7.2382x; 1.4298x over previous
//
#include <hip/hip_runtime.h>

#define NN   32
#define EMB  128
#define PEMB 64
#define ENCD 256
#define NLAY 4
#define W1C  261   // 2*EMB + 2*NCLS + 1
#define IND  193   // PEMB + 1 + EMB
#define UPAD 132   // padded row (floats): +16B breaks bank patterns

typedef __attribute__((ext_vector_type(8))) short short8;
typedef __attribute__((ext_vector_type(4))) float floatx4;

// tanh(x) = 1 - 2/(exp(2x)+1)
__device__ __forceinline__ float fast_tanh(float x) {
  float e = __expf(2.0f * x);
  return 1.0f - __fdividef(2.0f, e + 1.0f);
}
// fp32 -> bf16 RNE
__device__ __forceinline__ unsigned short f2bf(float x) {
  unsigned u = __float_as_uint(x);
  return (unsigned short)((u + 0x7fffu + ((u >> 16) & 1u)) >> 16);
}
__device__ __forceinline__ float bf2f(unsigned short h) {
  return __uint_as_float(((unsigned)h) << 16);
}

// A*B with A,B split hi/lo bf16 (drop lo*lo): 3 MFMAs
__device__ __forceinline__ floatx4 mfma3(short8 ah, short8 al, short8 bh, short8 bl, floatx4 acc) {
  acc = __builtin_amdgcn_mfma_f32_16x16x32_bf16(ah, bh, acc, 0, 0, 0);
  acc = __builtin_amdgcn_mfma_f32_16x16x32_bf16(al, bh, acc, 0, 0, 0);
  acc = __builtin_amdgcn_mfma_f32_16x16x32_bf16(ah, bl, acc, 0, 0, 0);
  return acc;
}

// convert 8 fp32 -> hi/lo bf16 short8
__device__ __forceinline__ void cvt8(const float* x, short8* hi, short8* lo) {
  #pragma unroll
  for (int m = 0; m < 8; m++) {
    const unsigned short hb = f2bf(x[m]);
    (*hi)[m] = (short)hb;
    (*lo)[m] = (short)f2bf(x[m] - bf2f(hb));
  }
}

// one fragment plane p (jt=p&1, kstep=p>>1) from fp32 [NN][UPAD] -> hi/lo frag LDS
__device__ __forceinline__ void cvt_plane(const float (*src)[UPAD],
                                          unsigned short (*dH)[64][8],
                                          unsigned short (*dL)[64][8],
                                          int p, int lane) {
  const int row  = (lane & 15) + ((p & 1) << 4);
  const int koff = ((p >> 1) << 5) + ((lane >> 4) << 3);
  float x[8];
  *(float4*)&x[0] = *(const float4*)&src[row][koff];
  *(float4*)&x[4] = *(const float4*)&src[row][koff + 4];
  short8 hi, lo;
  cvt8(x, &hi, &lo);
  *(short8*)&dH[p][lane][0] = hi;
  *(short8*)&dL[p][lane][0] = lo;
}

__device__ __forceinline__ float dot16_lds(const float* base, const float* wreg) {
  const float4 a = *(const float4*)(base);
  const float4 b = *(const float4*)(base + 4);
  const float4 c = *(const float4*)(base + 8);
  const float4 d = *(const float4*)(base + 12);
  return a.x*wreg[0] + a.y*wreg[1] + a.z*wreg[2]  + a.w*wreg[3]
       + b.x*wreg[4] + b.y*wreg[5] + b.z*wreg[6]  + b.w*wreg[7]
       + c.x*wreg[8] + c.y*wreg[9] + c.z*wreg[10] + c.w*wreg[11]
       + d.x*wreg[12]+ d.y*wreg[13]+ d.z*wreg[14] + d.w*wreg[15];
}

__global__ __launch_bounds__(512, 2) void fsd_fused(
    const float* __restrict__ pos, const float* __restrict__ enc,
    const float* __restrict__ pos_emb, const float* __restrict__ na_emb,
    const int* __restrict__ T,
    const float* __restrict__ fc1_w, const float* __restrict__ fc1_b,
    const float* __restrict__ fc2_w, const float* __restrict__ fc2_b,
    const float* __restrict__ lin_w, const float* __restrict__ lin_b,
    const float* __restrict__ msg_w1, const float* __restrict__ msg_b1,
    const float* __restrict__ msg_w2, const float* __restrict__ msg_b2,
    const float* __restrict__ upd_w1, const float* __restrict__ upd_b1,
    const float* __restrict__ upd_w2, const float* __restrict__ upd_b2,
    float* __restrict__ out)
{
  __shared__ __align__(16) float h32[NN][UPAD];     // fp32 h (residual base)
  __shared__ __align__(16) float u_s[NN][UPAD];     // also pos_emb staging
  __shared__ __align__(16) float v_s[NN][UPAD];
  __shared__ __align__(16) float ag32[NN][UPAD];    // aggr fp32; later hid32 (E1 out)
  __shared__ __align__(16) unsigned short hfH[8][64][8],  hfL[8][64][8];   // h A-frags
  __shared__ __align__(16) unsigned short agfH[8][64][8], agfL[8][64][8];  // aggr A-frags
  __shared__ __align__(16) unsigned short aT[2][8][64][8]; // t frags (D dbuf); reused as hid frags (E2)
  __shared__ float e_s[EMB];
  __shared__ float c5_s[EMB];
  __shared__ float clsU[2][EMB], clsV[2][EMB];
  __shared__ float enc_s[ENCD];
  __shared__ float hidA_s[64];
  __shared__ float posx_s[NN], posy_s[NN];
  __shared__ int   T_s[NN];

  const int b    = blockIdx.x;
  const int tid  = threadIdx.x;
  const int w    = tid >> 6, lane = tid & 63;   // 8 waves
  const int o    = tid & 127, g = tid >> 7;     // node-group mapping for VALU phases
  const int l15  = lane & 15, l4 = lane >> 4;

  // ---------------- Phase A: decoder_fc -> e_s ----------------
  if (tid < ENCD) enc_s[tid] = enc[b * ENCD + tid];
  if (tid < NN) {
    posx_s[tid] = pos[(b * NN + tid) * 2 + 0];
    posy_s[tid] = pos[(b * NN + tid) * 2 + 1];
    T_s[tid]    = T[b * NN + tid];
  }
  __syncthreads();
  if (tid < 64) {
    float a = fc1_b[tid];
    const float* wr = fc1_w + tid * ENCD;
    #pragma unroll 8
    for (int k = 0; k < ENCD; k++) a += enc_s[k] * wr[k];
    hidA_s[tid] = fast_tanh(a);
  }
  __syncthreads();
  if (tid < EMB) {
    float a = fc2_b[tid];
    const float* wr = fc2_w + tid * 64;
    #pragma unroll 8
    for (int k = 0; k < 64; k++) a += hidA_s[k] * wr[k];
    e_s[tid] = a;
  }
  float* pe_s = &u_s[0][0];   // stage pos_emb in u_s region (free until Phase C)
  for (int idx = tid; idx < NN * PEMB; idx += 512)
    pe_s[idx] = pos_emb[b * NN * PEMB + idx];
  __syncthreads();

  // ---------------- Phase B: h0 = x @ lin_w^T + lin_b (fp32, once) ----------------
  {
    const float nav = na_emb[b];
    const float* wr = lin_w + o * IND;
    float ebias = lin_b[o] + nav * wr[PEMB];
    #pragma unroll 8
    for (int k = 0; k < EMB; k++) ebias += e_s[k] * wr[65 + k];
    float acc[8];
    #pragma unroll
    for (int n = 0; n < 8; n++) acc[n] = ebias;
    for (int kc = 0; kc < PEMB; kc += 16) {
      float wreg[16];
      #pragma unroll
      for (int q = 0; q < 16; q++) wreg[q] = wr[kc + q];
      #pragma unroll
      for (int n = 0; n < 8; n++)
        acc[n] += dot16_lds(&pe_s[(g + 4 * n) * PEMB + kc], wreg);
    }
    __syncthreads();   // pe reads done before u_s reuse
    #pragma unroll
    for (int n = 0; n < 8; n++) h32[g + 4 * n][o] = acc[n];
  }
  __syncthreads();
  cvt_plane(h32, hfH, hfL, w, lane);   // h fragments for layer 0
  __syncthreads();

  // ---------------- Layer loop ----------------
  for (int l = 0; l < NLAY; l++) {
    const float* w1  = msg_w1 + l * EMB * W1C;
    const float* b1  = msg_b1 + l * EMB;
    const float* w2  = msg_w2 + l * EMB * EMB;
    const float* b2  = msg_b2 + l * EMB;
    const float* uw1 = upd_w1 + l * EMB * 2 * EMB;
    const float* ub1 = upd_b1 + l * EMB;
    const float* uw2 = upd_w2 + l * EMB * EMB;
    const float* ub2 = upd_b2 + l * EMB;

    // ---- stage c5 + class/bias tables ----
    if (tid < EMB) c5_s[tid] = w1[tid * W1C + 260];
    {
      const int c = (tid >> 7) & 1, oo = tid & 127;
      if (tid < 256) clsU[c][oo] = b1[oo] + w1[oo * W1C + 258 + c];
      else           clsV[c][oo] = w1[oo * W1C + 256 + c];
    }
    __syncthreads();   // (1) tables ready (h-frags ready from prev)

    // ---- Phase C: u,v = h @ W1parts^T via MFMA. wave w owns col-tiles {2w, 2w+1} of 16 ----
    {
      #pragma unroll
      for (int tt = 0; tt < 2; tt++) {
        const int tile = 2 * w + tt;
        const int part = tile >> 3;             // 0 -> u (W1 cols 0:128), 1 -> v (128:256)
        const int col  = ((tile & 7) << 4) + l15;
        const float* wb = w1 + col * W1C + part * EMB + (l4 << 3);
        floatx4 acc0 = {0.f,0.f,0.f,0.f}, acc1 = {0.f,0.f,0.f,0.f};
        #pragma unroll
        for (int ks = 0; ks < 4; ks++) {
          float x[8];
          #pragma unroll
          for (int m = 0; m < 8; m++) x[m] = wb[ks * 32 + m];   // W1C odd: scalar loads
          short8 bh, bl; cvt8(x, &bh, &bl);
          const short8 ah0 = *(const short8*)&hfH[ks*2+0][lane][0];
          const short8 al0 = *(const short8*)&hfL[ks*2+0][lane][0];
          const short8 ah1 = *(const short8*)&hfH[ks*2+1][lane][0];
          const short8 al1 = *(const short8*)&hfL[ks*2+1][lane][0];
          acc0 = mfma3(ah0, al0, bh, bl, acc0);
          acc1 = mfma3(ah1, al1, bh, bl, acc1);
        }
        float (*dst)[UPAD] = part ? v_s : u_s;
        const float (*tab)[EMB] = part ? clsV : clsU;
        #pragma unroll
        for (int q = 0; q < 4; q++) {
          const int r0 = (l4 << 2) + q;         // jt = 0
          const int r1 = r0 + 16;               // jt = 1
          dst[r0][col] = acc0[q] + tab[T_s[r0]][col];
          dst[r1][col] = acc1[q] + tab[T_s[r1]][col];
        }
      }
    }
    __syncthreads();   // (2) u,v ready

    // ---- Phase D prologue: W2 B-frags (regs), per-wave constants ----
    short8 whi[4], wlo[4];
    {
      const float* wbase = w2 + ((w << 4) + l15) * EMB + (l4 << 3);
      #pragma unroll
      for (int kt = 0; kt < 4; kt++) {
        float x[8];
        *(float4*)&x[0] = *(const float4*)(wbase + kt * 32);
        *(float4*)&x[4] = *(const float4*)(wbase + kt * 32 + 4);
        cvt8(x, &whi[kt], &wlo[kt]);
      }
    }
    const float b2r = b2[(w << 4) + l15];
    // wave w computes t-plane p = w: jt = w&1 (rows jD), kt = w>>1 (k range)
    const int jD    = l15 + ((w & 1) << 4);
    const int koffD = (l4 << 3) + ((w >> 1) << 5);
    float c5v[8], vv[8];
    *(float4*)&c5v[0] = *(const float4*)&c5_s[koffD];
    *(float4*)&c5v[4] = *(const float4*)&c5_s[koffD + 4];
    *(float4*)&vv[0]  = *(const float4*)&v_s[jD][koffD];
    *(float4*)&vv[4]  = *(const float4*)&v_s[jD][koffD + 4];
    const float pjx = posx_s[jD], pjy = posy_s[jD];

    // ---- Phase D: 32 dst nodes; t-frag build (lane-contiguous write) + MFMA + reduce ----
    for (int i = 0; i < NN; i++) {
      const int buf = i & 1;
      float uv[8];
      *(float4*)&uv[0] = *(const float4*)&u_s[i][koffD];
      *(float4*)&uv[4] = *(const float4*)&u_s[i][koffD + 4];
      const float dx = pjx - posx_s[i], dy = pjy - posy_s[i];
      const float d  = sqrtf(dx * dx + dy * dy);
      short8 tpk;
      #pragma unroll
      for (int m = 0; m < 8; m++)
        tpk[m] = (short)f2bf(fast_tanh(uv[m] + vv[m] + d * c5v[m]));
      *(short8*)&aT[buf][w][lane][0] = tpk;
      __syncthreads();

      floatx4 a0 = {0.f,0.f,0.f,0.f}, a1 = {0.f,0.f,0.f,0.f};
      #pragma unroll
      for (int ks = 0; ks < 4; ks++) {
        const short8 f0 = *(const short8*)&aT[buf][ks*2+0][lane][0];
        const short8 f1 = *(const short8*)&aT[buf][ks*2+1][lane][0];
        a0 = __builtin_amdgcn_mfma_f32_16x16x32_bf16(f0, wlo[ks], a0, 0, 0, 0);
        a0 = __builtin_amdgcn_mfma_f32_16x16x32_bf16(f0, whi[ks], a0, 0, 0, 0);
        a1 = __builtin_amdgcn_mfma_f32_16x16x32_bf16(f1, wlo[ks], a1, 0, 0, 0);
        a1 = __builtin_amdgcn_mfma_f32_16x16x32_bf16(f1, whi[ks], a1, 0, 0, 0);
      }
      float p = 0.f;
      #pragma unroll
      for (int q = 0; q < 4; q++)
        p += fast_tanh(a0[q] + b2r) + fast_tanh(a1[q] + b2r);
      p += __shfl_xor(p, 16);
      p += __shfl_xor(p, 32);
      if (lane < 16) ag32[i][(w << 4) + lane] = p;
    }
    __syncthreads();   // (3) ag32 complete

    cvt_plane(ag32, agfH, agfL, w, lane);
    __syncthreads();   // (4) aggr frags ready

    // ---- Phase E1: hid = tanh([h|aggr] @ uw1^T + ub1), wave w -> col-tile w ----
    {
      const int col = (w << 4) + l15;
      const float* wb = uw1 + col * (2 * EMB) + (l4 << 3);
      const float bo = ub1[col];
      floatx4 acc0 = {0.f,0.f,0.f,0.f}, acc1 = {0.f,0.f,0.f,0.f};
      #pragma unroll
      for (int ks = 0; ks < 8; ks++) {
        float x[8];
        *(float4*)&x[0] = *(const float4*)(wb + ks * 32);
        *(float4*)&x[4] = *(const float4*)(wb + ks * 32 + 4);
        short8 bh, bl; cvt8(x, &bh, &bl);
        short8 ah0, al0, ah1, al1;
        if (ks < 4) {
          ah0 = *(const short8*)&hfH[ks*2+0][lane][0];  al0 = *(const short8*)&hfL[ks*2+0][lane][0];
          ah1 = *(const short8*)&hfH[ks*2+1][lane][0];  al1 = *(const short8*)&hfL[ks*2+1][lane][0];
        } else {
          ah0 = *(const short8*)&agfH[(ks-4)*2+0][lane][0];  al0 = *(const short8*)&agfL[(ks-4)*2+0][lane][0];
          ah1 = *(const short8*)&agfH[(ks-4)*2+1][lane][0];  al1 = *(const short8*)&agfL[(ks-4)*2+1][lane][0];
        }
        acc0 = mfma3(ah0, al0, bh, bl, acc0);
        acc1 = mfma3(ah1, al1, bh, bl, acc1);
      }
      __syncthreads();   // (5) all agf/hf reads done before ag32 rewrite below
      #pragma unroll
      for (int q = 0; q < 4; q++) {
        const int r0 = (l4 << 2) + q, r1 = r0 + 16;
        ag32[r0][col] = fast_tanh(acc0[q] + bo);   // ag32 reused as hid32
        ag32[r1][col] = fast_tanh(acc1[q] + bo);
      }
    }
    __syncthreads();   // (6) hid32 ready

    cvt_plane(ag32, aT[0], aT[1], w, lane);   // hid frags into aT (D done with it)
    __syncthreads();   // (7)

    // ---- Phase E2: h += tanh(hid @ uw2^T + ub2), wave w -> col-tile w ----
    {
      const int col = (w << 4) + l15;
      const float* wb = uw2 + col * EMB + (l4 << 3);
      const float bo = ub2[col];
      floatx4 acc0 = {0.f,0.f,0.f,0.f}, acc1 = {0.f,0.f,0.f,0.f};
      #pragma unroll
      for (int ks = 0; ks < 4; ks++) {
        float x[8];
        *(float4*)&x[0] = *(const float4*)(wb + ks * 32);
        *(float4*)&x[4] = *(const float4*)(wb + ks * 32 + 4);
        short8 bh, bl; cvt8(x, &bh, &bl);
        const short8 ah0 = *(const short8*)&aT[0][ks*2+0][lane][0];
        const short8 al0 = *(const short8*)&aT[1][ks*2+0][lane][0];
        const short8 ah1 = *(const short8*)&aT[0][ks*2+1][lane][0];
        const short8 al1 = *(const short8*)&aT[1][ks*2+1][lane][0];
        acc0 = mfma3(ah0, al0, bh, bl, acc0);
        acc1 = mfma3(ah1, al1, bh, bl, acc1);
      }
      #pragma unroll
      for (int q = 0; q < 4; q++) {
        const int r0 = (l4 << 2) + q, r1 = r0 + 16;
        h32[r0][col] += fast_tanh(acc0[q] + bo);
        h32[r1][col] += fast_tanh(acc1[q] + bo);
      }
    }
    __syncthreads();   // (8) h updated

    if (l + 1 < NLAY) {
      cvt_plane(h32, hfH, hfL, w, lane);
      __syncthreads();
    }
  }

  // ---------------- write out ----------------
  for (int idx = tid; idx < NN * EMB; idx += 512)
    out[b * NN * EMB + idx] = h32[idx >> 7][idx & 127];
}

extern "C" void kernel_launch(void* const* d_in, const int* in_sizes, int n_in,
                              void* d_out, int out_size, void* d_ws, size_t ws_size,
                              hipStream_t stream) {
  const float* pos     = (const float*)d_in[0];
  const float* enc     = (const float*)d_in[1];
  const float* pos_emb = (const float*)d_in[2];
  const float* na_emb  = (const float*)d_in[3];
  const int*   T       = (const int*)d_in[4];
  // d_in[5] = num_agents (compile-time 32)
  const float* fc1_w = (const float*)d_in[6];
  const float* fc1_b = (const float*)d_in[7];
  const float* fc2_w = (const float*)d_in[8];
  const float* fc2_b = (const float*)d_in[9];
  const float* lin_w = (const float*)d_in[10];
  const float* lin_b = (const float*)d_in[11];
  const float* msg_w1 = (const float*)d_in[12];
  const float* msg_b1 = (const float*)d_in[13];
  const float* msg_w2 = (const float*)d_in[14];
  const float* msg_b2 = (const float*)d_in[15];
  const float* upd_w1 = (const float*)d_in[16];
  const float* upd_b1 = (const float*)d_in[17];
  const float* upd_w2 = (const float*)d_in[18];
  const float* upd_b2 = (const float*)d_in[19];

  fsd_fused<<<256, 512, 0, stream>>>(pos, enc, pos_emb, na_emb, T,
      fc1_w, fc1_b, fc2_w, fc2_b, lin_w, lin_b,
      msg_w1, msg_b1, msg_w2, msg_b2, upd_w1, upd_b1, upd_w2, upd_b2,
      (float*)d_out);
}

// Round 5
// 261.230 us; speedup vs baseline: 7.9073x; 1.0924x over previous
//
#include <hip/hip_runtime.h>

#define NN   32
#define EMB  128
#define PEMB 64
#define ENCD 256
#define NLAY 4
#define W1C  261   // 2*EMB + 2*NCLS + 1
#define IND  193   // PEMB + 1 + EMB
#define UPAD 132   // padded row (floats): +16B breaks bank patterns

typedef __attribute__((ext_vector_type(8))) short short8;
typedef __attribute__((ext_vector_type(4))) float floatx4;

// ---- pre-converted weight fragments (bf16 hi/lo), filled by wconv kernel ----
__device__ unsigned short g_wC_h[16384 * 8], g_wC_l[16384 * 8];   // W1 frags
__device__ unsigned short g_wD_h[8192 * 8],  g_wD_l[8192 * 8];    // W2 frags
__device__ unsigned short g_wE1_h[16384 * 8], g_wE1_l[16384 * 8]; // UW1 frags
__device__ unsigned short g_wE2_h[8192 * 8],  g_wE2_l[8192 * 8];  // UW2 frags

// tanh(x) = 1 - 2/(exp(2x)+1)
__device__ __forceinline__ float fast_tanh(float x) {
  float e = __expf(2.0f * x);
  return 1.0f - __fdividef(2.0f, e + 1.0f);
}
// fp32 -> bf16 RNE (exact, used in pre-kernel only)
__device__ __forceinline__ unsigned short f2bf(float x) {
  unsigned u = __float_as_uint(x);
  return (unsigned short)((u + 0x7fffu + ((u >> 16) & 1u)) >> 16);
}
__device__ __forceinline__ float bf2f(unsigned short h) {
  return __uint_as_float(((unsigned)h) << 16);
}
// hw packed convert: dst.lo16 = bf16(a), dst.hi16 = bf16(b)
__device__ __forceinline__ unsigned cvtpk(float a, float b) {
  unsigned r;
  asm("v_cvt_pk_bf16_f32 %0, %1, %2" : "=v"(r) : "v"(a), "v"(b));
  return r;
}

// A*B with A,B split hi/lo bf16 (drop lo*lo): 3 MFMAs
__device__ __forceinline__ floatx4 mfma3(short8 ah, short8 al, short8 bh, short8 bl, floatx4 acc) {
  acc = __builtin_amdgcn_mfma_f32_16x16x32_bf16(ah, bh, acc, 0, 0, 0);
  acc = __builtin_amdgcn_mfma_f32_16x16x32_bf16(al, bh, acc, 0, 0, 0);
  acc = __builtin_amdgcn_mfma_f32_16x16x32_bf16(ah, bl, acc, 0, 0, 0);
  return acc;
}

// one fragment plane p (jt=p&1, kstep=p>>1) from fp32 [NN][UPAD] -> hi/lo frag LDS
__device__ __forceinline__ void cvt_plane(const float (*src)[UPAD],
                                          unsigned short (*dH)[64][8],
                                          unsigned short (*dL)[64][8],
                                          int p, int lane) {
  const int row  = (lane & 15) + ((p & 1) << 4);
  const int koff = ((p >> 1) << 5) + ((lane >> 4) << 3);
  float x[8];
  *(float4*)&x[0] = *(const float4*)&src[row][koff];
  *(float4*)&x[4] = *(const float4*)&src[row][koff + 4];
  unsigned h[4], lo[4];
  #pragma unroll
  for (int q = 0; q < 4; q++) {
    h[q] = cvtpk(x[2*q], x[2*q+1]);
    const float r0 = x[2*q]   - __uint_as_float(h[q] << 16);
    const float r1 = x[2*q+1] - __uint_as_float(h[q] & 0xffff0000u);
    lo[q] = cvtpk(r0, r1);
  }
  *(uint4*)&dH[p][lane][0] = make_uint4(h[0], h[1], h[2], h[3]);
  *(uint4*)&dL[p][lane][0] = make_uint4(lo[0], lo[1], lo[2], lo[3]);
}

__device__ __forceinline__ float dot16_lds(const float* base, const float* wreg) {
  const float4 a = *(const float4*)(base);
  const float4 b = *(const float4*)(base + 4);
  const float4 c = *(const float4*)(base + 8);
  const float4 d = *(const float4*)(base + 12);
  return a.x*wreg[0] + a.y*wreg[1] + a.z*wreg[2]  + a.w*wreg[3]
       + b.x*wreg[4] + b.y*wreg[5] + b.z*wreg[6]  + b.w*wreg[7]
       + c.x*wreg[8] + c.y*wreg[9] + c.z*wreg[10] + c.w*wreg[11]
       + d.x*wreg[12]+ d.y*wreg[13]+ d.z*wreg[14] + d.w*wreg[15];
}

// ---------------- weight pre-conversion: fp32 -> frag-ordered bf16 hi/lo ----------------
__global__ __launch_bounds__(256) void wconv(
    const float* __restrict__ msg_w1, const float* __restrict__ msg_w2,
    const float* __restrict__ upd_w1, const float* __restrict__ upd_w2) {
  const int t = blockIdx.x * 256 + threadIdx.x;
  const float* src;
  unsigned short *dh, *dl;
  if (t < 16384) {                               // W1 (Phase C): [l][tile][ks][lane][8]
    const int lane = t & 63, ks = (t >> 6) & 3, tile = (t >> 8) & 15, l = t >> 12;
    src = msg_w1 + l * EMB * W1C + (((tile & 7) << 4) + (lane & 15)) * W1C
        + (tile >> 3) * EMB + ks * 32 + ((lane >> 4) << 3);
    dh = g_wC_h + t * 8; dl = g_wC_l + t * 8;
  } else if (t < 24576) {                        // W2 (Phase D): [l][w][kt][lane][8]
    const int r = t - 16384;
    const int lane = r & 63, kt = (r >> 6) & 3, w = (r >> 8) & 7, l = r >> 11;
    src = msg_w2 + l * EMB * EMB + ((w << 4) + (lane & 15)) * EMB + kt * 32 + ((lane >> 4) << 3);
    dh = g_wD_h + r * 8; dl = g_wD_l + r * 8;
  } else if (t < 40960) {                        // UW1 (E1): [l][w][ks(8)][lane][8]
    const int r = t - 24576;
    const int lane = r & 63, ks = (r >> 6) & 7, w = (r >> 9) & 7, l = r >> 12;
    src = upd_w1 + l * EMB * 2 * EMB + ((w << 4) + (lane & 15)) * 2 * EMB + ks * 32 + ((lane >> 4) << 3);
    dh = g_wE1_h + r * 8; dl = g_wE1_l + r * 8;
  } else if (t < 49152) {                        // UW2 (E2): [l][w][ks(4)][lane][8]
    const int r = t - 40960;
    const int lane = r & 63, ks = (r >> 6) & 3, w = (r >> 8) & 7, l = r >> 11;
    src = upd_w2 + l * EMB * EMB + ((w << 4) + (lane & 15)) * EMB + ks * 32 + ((lane >> 4) << 3);
    dh = g_wE2_h + r * 8; dl = g_wE2_l + r * 8;
  } else return;
  unsigned short hh[8], ll[8];
  #pragma unroll
  for (int m = 0; m < 8; m++) {
    const float x = src[m];
    const unsigned short hb = f2bf(x);
    hh[m] = hb;
    ll[m] = f2bf(x - bf2f(hb));
  }
  *(short8*)dh = *(const short8*)hh;
  *(short8*)dl = *(const short8*)ll;
}

__global__ __launch_bounds__(512, 1) void fsd_fused(
    const float* __restrict__ pos, const float* __restrict__ enc,
    const float* __restrict__ pos_emb, const float* __restrict__ na_emb,
    const int* __restrict__ T,
    const float* __restrict__ fc1_w, const float* __restrict__ fc1_b,
    const float* __restrict__ fc2_w, const float* __restrict__ fc2_b,
    const float* __restrict__ lin_w, const float* __restrict__ lin_b,
    const float* __restrict__ msg_w1, const float* __restrict__ msg_b1,
    const float* __restrict__ msg_b2,
    const float* __restrict__ upd_b1, const float* __restrict__ upd_b2,
    float* __restrict__ out)
{
  __shared__ __align__(16) float h32[NN][UPAD];
  __shared__ __align__(16) float u_s[NN][UPAD];     // pos_emb staging; hid32 in E1
  __shared__ __align__(16) float v_s[NN][UPAD];
  __shared__ __align__(16) float ag32[NN][UPAD];
  __shared__ __align__(16) unsigned short hfH[8][64][8],  hfL[8][64][8];   // h A-frags
  __shared__ __align__(16) unsigned short agfH[8][64][8], agfL[8][64][8];  // aggr A-frags
  __shared__ __align__(16) unsigned short aT[4][8][64][8]; // t frags, 2-dst x dbuf; hid frags in E2
  __shared__ float e_s[EMB];
  __shared__ float c5_s[EMB];
  __shared__ float clsU[2][EMB], clsV[2][EMB];
  __shared__ float enc_s[ENCD];
  __shared__ float hidA_s[64];
  __shared__ float posx_s[NN], posy_s[NN];
  __shared__ int   T_s[NN];

  const int b    = blockIdx.x;
  const int tid  = threadIdx.x;
  const int w    = tid >> 6, lane = tid & 63;   // 8 waves
  const int o    = tid & 127, g = tid >> 7;     // node-group mapping for VALU phases
  const int l15  = lane & 15, l4 = lane >> 4;

  // ---------------- Phase A: decoder_fc -> e_s ----------------
  if (tid < ENCD) enc_s[tid] = enc[b * ENCD + tid];
  if (tid < NN) {
    posx_s[tid] = pos[(b * NN + tid) * 2 + 0];
    posy_s[tid] = pos[(b * NN + tid) * 2 + 1];
    T_s[tid]    = T[b * NN + tid];
  }
  __syncthreads();
  if (tid < 64) {
    float a = fc1_b[tid];
    const float* wr = fc1_w + tid * ENCD;
    #pragma unroll 8
    for (int k = 0; k < ENCD; k++) a += enc_s[k] * wr[k];
    hidA_s[tid] = fast_tanh(a);
  }
  __syncthreads();
  if (tid < EMB) {
    float a = fc2_b[tid];
    const float* wr = fc2_w + tid * 64;
    #pragma unroll 8
    for (int k = 0; k < 64; k++) a += hidA_s[k] * wr[k];
    e_s[tid] = a;
  }
  float* pe_s = &u_s[0][0];
  for (int idx = tid; idx < NN * PEMB; idx += 512)
    pe_s[idx] = pos_emb[b * NN * PEMB + idx];
  __syncthreads();

  // ---------------- Phase B: h0 = x @ lin_w^T + lin_b ----------------
  {
    const float nav = na_emb[b];
    const float* wr = lin_w + o * IND;
    float ebias = lin_b[o] + nav * wr[PEMB];
    #pragma unroll 8
    for (int k = 0; k < EMB; k++) ebias += e_s[k] * wr[65 + k];
    float acc[8];
    #pragma unroll
    for (int n = 0; n < 8; n++) acc[n] = ebias;
    for (int kc = 0; kc < PEMB; kc += 16) {
      float wreg[16];
      #pragma unroll
      for (int q = 0; q < 16; q++) wreg[q] = wr[kc + q];
      #pragma unroll
      for (int n = 0; n < 8; n++)
        acc[n] += dot16_lds(&pe_s[(g + 4 * n) * PEMB + kc], wreg);
    }
    __syncthreads();   // pe reads done before u_s reuse
    #pragma unroll
    for (int n = 0; n < 8; n++) h32[g + 4 * n][o] = acc[n];
  }
  __syncthreads();
  cvt_plane(h32, hfH, hfL, w, lane);
  __syncthreads();

  // ---------------- Layer loop ----------------
  for (int l = 0; l < NLAY; l++) {
    const float* b1  = msg_b1 + l * EMB;
    const float* b2  = msg_b2 + l * EMB;
    const float* ub1 = upd_b1 + l * EMB;
    const float* ub2 = upd_b2 + l * EMB;
    const float* w1  = msg_w1 + l * EMB * W1C;   // only for c5/cls columns

    if (tid < EMB) c5_s[tid] = w1[tid * W1C + 260];
    {
      const int c = (tid >> 7) & 1, oo = tid & 127;
      if (tid < 256) clsU[c][oo] = b1[oo] + w1[oo * W1C + 258 + c];
      else           clsV[c][oo] = w1[oo * W1C + 256 + c];
    }
    __syncthreads();   // (1) tables ready, h-frags ready

    // ---- Phase C: u,v = h @ W1parts^T via MFMA; B-frags from g_wC ----
    {
      #pragma unroll
      for (int tt = 0; tt < 2; tt++) {
        const int tile = 2 * w + tt;
        const int part = tile >> 3;
        const int col  = ((tile & 7) << 4) + l15;
        floatx4 acc0 = {0.f,0.f,0.f,0.f}, acc1 = {0.f,0.f,0.f,0.f};
        #pragma unroll
        for (int ks = 0; ks < 4; ks++) {
          const int idx = (((l * 16 + tile) * 4 + ks) * 64 + lane) * 8;
          const short8 bh = *(const short8*)(g_wC_h + idx);
          const short8 bl = *(const short8*)(g_wC_l + idx);
          const short8 ah0 = *(const short8*)&hfH[ks*2+0][lane][0];
          const short8 al0 = *(const short8*)&hfL[ks*2+0][lane][0];
          const short8 ah1 = *(const short8*)&hfH[ks*2+1][lane][0];
          const short8 al1 = *(const short8*)&hfL[ks*2+1][lane][0];
          acc0 = mfma3(ah0, al0, bh, bl, acc0);
          acc1 = mfma3(ah1, al1, bh, bl, acc1);
        }
        float (*dst)[UPAD] = part ? v_s : u_s;
        const float (*tab)[EMB] = part ? clsV : clsU;
        #pragma unroll
        for (int q = 0; q < 4; q++) {
          const int r0 = (l4 << 2) + q;
          const int r1 = r0 + 16;
          dst[r0][col] = acc0[q] + tab[T_s[r0]][col];
          dst[r1][col] = acc1[q] + tab[T_s[r1]][col];
        }
      }
    }
    __syncthreads();   // (2) u,v ready

    // ---- Phase D prologue: W2 B-frags from g_wD; per-wave constants ----
    short8 whi[4], wlo[4];
    #pragma unroll
    for (int kt = 0; kt < 4; kt++) {
      const int idx = (((l * 8 + w) * 4 + kt) * 64 + lane) * 8;
      whi[kt] = *(const short8*)(g_wD_h + idx);
      wlo[kt] = *(const short8*)(g_wD_l + idx);
    }
    const float b2r = b2[(w << 4) + l15];
    const int jD    = l15 + ((w & 1) << 4);       // plane p = w: jt=w&1, kt=w>>1
    const int koffD = (l4 << 3) + ((w >> 1) << 5);
    float c5v[8], vv[8];
    *(float4*)&c5v[0] = *(const float4*)&c5_s[koffD];
    *(float4*)&c5v[4] = *(const float4*)&c5_s[koffD + 4];
    *(float4*)&vv[0]  = *(const float4*)&v_s[jD][koffD];
    *(float4*)&vv[4]  = *(const float4*)&v_s[jD][koffD + 4];
    const float pjx = posx_s[jD], pjy = posy_s[jD];

    // ---- Phase D: 2 dst per barrier (4-buffer t staging) ----
    for (int s = 0; s < 16; s++) {
      const int pb = (s & 1) << 1;
      // build t for i0 = 2s and i1 = 2s+1
      #pragma unroll
      for (int half = 0; half < 2; half++) {
        const int i = 2 * s + half;
        float uv[8];
        *(float4*)&uv[0] = *(const float4*)&u_s[i][koffD];
        *(float4*)&uv[4] = *(const float4*)&u_s[i][koffD + 4];
        const float dx = pjx - posx_s[i], dy = pjy - posy_s[i];
        const float d  = sqrtf(dx * dx + dy * dy);
        float tv[8];
        #pragma unroll
        for (int m = 0; m < 8; m++)
          tv[m] = fast_tanh(uv[m] + vv[m] + d * c5v[m]);
        unsigned pk0 = cvtpk(tv[0], tv[1]), pk1 = cvtpk(tv[2], tv[3]);
        unsigned pk2 = cvtpk(tv[4], tv[5]), pk3 = cvtpk(tv[6], tv[7]);
        *(uint4*)&aT[pb + half][w][lane][0] = make_uint4(pk0, pk1, pk2, pk3);
      }
      __syncthreads();   // publish t(i0), t(i1); also fences pair pb reads from s-2

      #pragma unroll
      for (int half = 0; half < 2; half++) {
        const int i = 2 * s + half;
        floatx4 a0 = {0.f,0.f,0.f,0.f}, a1 = {0.f,0.f,0.f,0.f};
        #pragma unroll
        for (int ks = 0; ks < 4; ks++) {
          const short8 f0 = *(const short8*)&aT[pb + half][ks*2+0][lane][0];
          const short8 f1 = *(const short8*)&aT[pb + half][ks*2+1][lane][0];
          a0 = __builtin_amdgcn_mfma_f32_16x16x32_bf16(f0, wlo[ks], a0, 0, 0, 0);
          a0 = __builtin_amdgcn_mfma_f32_16x16x32_bf16(f0, whi[ks], a0, 0, 0, 0);
          a1 = __builtin_amdgcn_mfma_f32_16x16x32_bf16(f1, wlo[ks], a1, 0, 0, 0);
          a1 = __builtin_amdgcn_mfma_f32_16x16x32_bf16(f1, whi[ks], a1, 0, 0, 0);
        }
        float p = 0.f;
        #pragma unroll
        for (int q = 0; q < 4; q++)
          p += fast_tanh(a0[q] + b2r) + fast_tanh(a1[q] + b2r);
        p += __shfl_xor(p, 16);
        p += __shfl_xor(p, 32);
        if (lane < 16) ag32[i][(w << 4) + lane] = p;
      }
    }
    __syncthreads();   // (3) ag32 complete

    cvt_plane(ag32, agfH, agfL, w, lane);
    __syncthreads();   // (4) aggr frags ready

    // ---- Phase E1: hid = tanh([h|aggr] @ uw1^T + ub1) -> u_s (free buffer) ----
    {
      const int col = (w << 4) + l15;
      const float bo = ub1[col];
      floatx4 acc0 = {0.f,0.f,0.f,0.f}, acc1 = {0.f,0.f,0.f,0.f};
      #pragma unroll
      for (int ks = 0; ks < 8; ks++) {
        const int idx = (((l * 8 + w) * 8 + ks) * 64 + lane) * 8;
        const short8 bh = *(const short8*)(g_wE1_h + idx);
        const short8 bl = *(const short8*)(g_wE1_l + idx);
        short8 ah0, al0, ah1, al1;
        if (ks < 4) {
          ah0 = *(const short8*)&hfH[ks*2+0][lane][0];  al0 = *(const short8*)&hfL[ks*2+0][lane][0];
          ah1 = *(const short8*)&hfH[ks*2+1][lane][0];  al1 = *(const short8*)&hfL[ks*2+1][lane][0];
        } else {
          ah0 = *(const short8*)&agfH[(ks-4)*2+0][lane][0];  al0 = *(const short8*)&agfL[(ks-4)*2+0][lane][0];
          ah1 = *(const short8*)&agfH[(ks-4)*2+1][lane][0];  al1 = *(const short8*)&agfL[(ks-4)*2+1][lane][0];
        }
        acc0 = mfma3(ah0, al0, bh, bl, acc0);
        acc1 = mfma3(ah1, al1, bh, bl, acc1);
      }
      #pragma unroll
      for (int q = 0; q < 4; q++) {
        const int r0 = (l4 << 2) + q, r1 = r0 + 16;
        u_s[r0][col] = fast_tanh(acc0[q] + bo);   // u_s reused as hid32
        u_s[r1][col] = fast_tanh(acc1[q] + bo);
      }
    }
    __syncthreads();   // (5) hid32 ready

    cvt_plane(u_s, aT[0], aT[1], w, lane);   // hid frags into aT (D done with it)
    __syncthreads();   // (6)

    // ---- Phase E2: h += tanh(hid @ uw2^T + ub2) ----
    {
      const int col = (w << 4) + l15;
      const float bo = ub2[col];
      floatx4 acc0 = {0.f,0.f,0.f,0.f}, acc1 = {0.f,0.f,0.f,0.f};
      #pragma unroll
      for (int ks = 0; ks < 4; ks++) {
        const int idx = (((l * 8 + w) * 4 + ks) * 64 + lane) * 8;
        const short8 bh = *(const short8*)(g_wE2_h + idx);
        const short8 bl = *(const short8*)(g_wE2_l + idx);
        const short8 ah0 = *(const short8*)&aT[0][ks*2+0][lane][0];
        const short8 al0 = *(const short8*)&aT[1][ks*2+0][lane][0];
        const short8 ah1 = *(const short8*)&aT[0][ks*2+1][lane][0];
        const short8 al1 = *(const short8*)&aT[1][ks*2+1][lane][0];
        acc0 = mfma3(ah0, al0, bh, bl, acc0);
        acc1 = mfma3(ah1, al1, bh, bl, acc1);
      }
      #pragma unroll
      for (int q = 0; q < 4; q++) {
        const int r0 = (l4 << 2) + q, r1 = r0 + 16;
        h32[r0][col] += fast_tanh(acc0[q] + bo);
        h32[r1][col] += fast_tanh(acc1[q] + bo);
      }
    }
    __syncthreads();   // (7) h updated

    if (l + 1 < NLAY) {
      cvt_plane(h32, hfH, hfL, w, lane);
      __syncthreads();
    }
  }

  // ---------------- write out ----------------
  for (int idx = tid; idx < NN * EMB; idx += 512)
    out[b * NN * EMB + idx] = h32[idx >> 7][idx & 127];
}

extern "C" void kernel_launch(void* const* d_in, const int* in_sizes, int n_in,
                              void* d_out, int out_size, void* d_ws, size_t ws_size,
                              hipStream_t stream) {
  const float* pos     = (const float*)d_in[0];
  const float* enc     = (const float*)d_in[1];
  const float* pos_emb = (const float*)d_in[2];
  const float* na_emb  = (const float*)d_in[3];
  const int*   T       = (const int*)d_in[4];
  // d_in[5] = num_agents (compile-time 32)
  const float* fc1_w = (const float*)d_in[6];
  const float* fc1_b = (const float*)d_in[7];
  const float* fc2_w = (const float*)d_in[8];
  const float* fc2_b = (const float*)d_in[9];
  const float* lin_w = (const float*)d_in[10];
  const float* lin_b = (const float*)d_in[11];
  const float* msg_w1 = (const float*)d_in[12];
  const float* msg_b1 = (const float*)d_in[13];
  const float* msg_w2 = (const float*)d_in[14];
  const float* msg_b2 = (const float*)d_in[15];
  const float* upd_w1 = (const float*)d_in[16];
  const float* upd_b1 = (const float*)d_in[17];
  const float* upd_w2 = (const float*)d_in[18];
  const float* upd_b2 = (const float*)d_in[19];

  wconv<<<192, 256, 0, stream>>>(msg_w1, msg_w2, upd_w1, upd_w2);
  fsd_fused<<<256, 512, 0, stream>>>(pos, enc, pos_emb, na_emb, T,
      fc1_w, fc1_b, fc2_w, fc2_b, lin_w, lin_b,
      msg_w1, msg_b1, msg_b2, upd_b1, upd_b2,
      (float*)d_out);
}

// Round 6
// 257.395 us; speedup vs baseline: 8.0251x; 1.0149x over previous
//
#include <hip/hip_runtime.h>

#define NN   32
#define EMB  128
#define PEMB 64
#define ENCD 256
#define NLAY 4
#define W1C  261   // 2*EMB + 2*NCLS + 1
#define IND  193   // PEMB + 1 + EMB
#define UPAD 132   // padded row (floats): +16B breaks bank patterns

typedef __attribute__((ext_vector_type(8))) short short8;
typedef __attribute__((ext_vector_type(4))) float floatx4;

// ---- pre-converted weight fragments (bf16 hi/lo), filled by wconv kernel ----
__device__ unsigned short g_wC_h[16384 * 8], g_wC_l[16384 * 8];   // W1 frags
__device__ unsigned short g_wD_h[8192 * 8],  g_wD_l[8192 * 8];    // W2 frags
__device__ unsigned short g_wE1_h[16384 * 8], g_wE1_l[16384 * 8]; // UW1 frags
__device__ unsigned short g_wE2_h[8192 * 8],  g_wE2_l[8192 * 8];  // UW2 frags

// tanh(x) = 1 - 2/(exp(2x)+1)
__device__ __forceinline__ float fast_tanh(float x) {
  float e = __expf(2.0f * x);
  return 1.0f - __fdividef(2.0f, e + 1.0f);
}
// fp32 -> bf16 RNE
__device__ __forceinline__ unsigned short f2bf(float x) {
  unsigned u = __float_as_uint(x);
  return (unsigned short)((u + 0x7fffu + ((u >> 16) & 1u)) >> 16);
}
__device__ __forceinline__ float bf2f(unsigned short h) {
  return __uint_as_float(((unsigned)h) << 16);
}
// hw packed convert: dst.lo16 = bf16(a), dst.hi16 = bf16(b)
__device__ __forceinline__ unsigned cvtpk(float a, float b) {
  unsigned r;
  asm("v_cvt_pk_bf16_f32 %0, %1, %2" : "=v"(r) : "v"(a), "v"(b));
  return r;
}

// A*B with A,B split hi/lo bf16 (drop lo*lo): 3 MFMAs
__device__ __forceinline__ floatx4 mfma3(short8 ah, short8 al, short8 bh, short8 bl, floatx4 acc) {
  acc = __builtin_amdgcn_mfma_f32_16x16x32_bf16(ah, bh, acc, 0, 0, 0);
  acc = __builtin_amdgcn_mfma_f32_16x16x32_bf16(al, bh, acc, 0, 0, 0);
  acc = __builtin_amdgcn_mfma_f32_16x16x32_bf16(ah, bl, acc, 0, 0, 0);
  return acc;
}

// one fragment plane p (jt=p&1, kstep=p>>1) from fp32 [NN][UPAD] -> hi/lo frag LDS
__device__ __forceinline__ void cvt_plane(const float (*src)[UPAD],
                                          unsigned short (*dH)[64][8],
                                          unsigned short (*dL)[64][8],
                                          int p, int lane) {
  const int row  = (lane & 15) + ((p & 1) << 4);
  const int koff = ((p >> 1) << 5) + ((lane >> 4) << 3);
  float x[8];
  *(float4*)&x[0] = *(const float4*)&src[row][koff];
  *(float4*)&x[4] = *(const float4*)&src[row][koff + 4];
  unsigned h[4], lo[4];
  #pragma unroll
  for (int q = 0; q < 4; q++) {
    h[q] = cvtpk(x[2*q], x[2*q+1]);
    const float r0 = x[2*q]   - __uint_as_float(h[q] << 16);
    const float r1 = x[2*q+1] - __uint_as_float(h[q] & 0xffff0000u);
    lo[q] = cvtpk(r0, r1);
  }
  *(uint4*)&dH[p][lane][0] = make_uint4(h[0], h[1], h[2], h[3]);
  *(uint4*)&dL[p][lane][0] = make_uint4(lo[0], lo[1], lo[2], lo[3]);
}

__device__ __forceinline__ float dot16_lds(const float* base, const float* wreg) {
  const float4 a = *(const float4*)(base);
  const float4 b = *(const float4*)(base + 4);
  const float4 c = *(const float4*)(base + 8);
  const float4 d = *(const float4*)(base + 12);
  return a.x*wreg[0] + a.y*wreg[1] + a.z*wreg[2]  + a.w*wreg[3]
       + b.x*wreg[4] + b.y*wreg[5] + b.z*wreg[6]  + b.w*wreg[7]
       + c.x*wreg[8] + c.y*wreg[9] + c.z*wreg[10] + c.w*wreg[11]
       + d.x*wreg[12]+ d.y*wreg[13]+ d.z*wreg[14] + d.w*wreg[15];
}

// ---------------- weight pre-conversion: fp32 -> frag-ordered bf16 hi/lo ----------------
__global__ __launch_bounds__(256) void wconv(
    const float* __restrict__ msg_w1, const float* __restrict__ msg_w2,
    const float* __restrict__ upd_w1, const float* __restrict__ upd_w2) {
  const int t = blockIdx.x * 256 + threadIdx.x;
  const float* src;
  unsigned short *dh, *dl;
  if (t < 16384) {                               // W1 (Phase C): [l][tile][ks][lane][8]
    const int lane = t & 63, ks = (t >> 6) & 3, tile = (t >> 8) & 15, l = t >> 12;
    src = msg_w1 + l * EMB * W1C + (((tile & 7) << 4) + (lane & 15)) * W1C
        + (tile >> 3) * EMB + ks * 32 + ((lane >> 4) << 3);
    dh = g_wC_h + t * 8; dl = g_wC_l + t * 8;
  } else if (t < 24576) {                        // W2 (Phase D): [l][ct][ks][lane][8]
    const int r = t - 16384;
    const int lane = r & 63, ks = (r >> 6) & 3, ct = (r >> 8) & 7, l = r >> 11;
    src = msg_w2 + l * EMB * EMB + ((ct << 4) + (lane & 15)) * EMB + ks * 32 + ((lane >> 4) << 3);
    dh = g_wD_h + r * 8; dl = g_wD_l + r * 8;
  } else if (t < 40960) {                        // UW1 (E1): [l][w][ks(8)][lane][8]
    const int r = t - 24576;
    const int lane = r & 63, ks = (r >> 6) & 7, w = (r >> 9) & 7, l = r >> 12;
    src = upd_w1 + l * EMB * 2 * EMB + ((w << 4) + (lane & 15)) * 2 * EMB + ks * 32 + ((lane >> 4) << 3);
    dh = g_wE1_h + r * 8; dl = g_wE1_l + r * 8;
  } else if (t < 49152) {                        // UW2 (E2): [l][w][ks(4)][lane][8]
    const int r = t - 40960;
    const int lane = r & 63, ks = (r >> 6) & 3, w = (r >> 8) & 7, l = r >> 11;
    src = upd_w2 + l * EMB * EMB + ((w << 4) + (lane & 15)) * EMB + ks * 32 + ((lane >> 4) << 3);
    dh = g_wE2_h + r * 8; dl = g_wE2_l + r * 8;
  } else return;
  unsigned short hh[8], ll[8];
  #pragma unroll
  for (int m = 0; m < 8; m++) {
    const float x = src[m];
    const unsigned short hb = f2bf(x);
    hh[m] = hb;
    ll[m] = f2bf(x - bf2f(hb));
  }
  *(short8*)dh = *(const short8*)hh;
  *(short8*)dl = *(const short8*)ll;
}

__global__ __launch_bounds__(512, 2) void fsd_fused(
    const float* __restrict__ pos, const float* __restrict__ enc,
    const float* __restrict__ pos_emb, const float* __restrict__ na_emb,
    const int* __restrict__ T,
    const float* __restrict__ fc1_w, const float* __restrict__ fc1_b,
    const float* __restrict__ fc2_w, const float* __restrict__ fc2_b,
    const float* __restrict__ lin_w, const float* __restrict__ lin_b,
    const float* __restrict__ msg_w1, const float* __restrict__ msg_b1,
    const float* __restrict__ msg_b2,
    const float* __restrict__ upd_b1, const float* __restrict__ upd_b2,
    float* __restrict__ out)
{
  __shared__ __align__(16) float h32[NN][UPAD];     // 16.9 KB (residual base)
  __shared__ __align__(16) float u_s[NN][UPAD];     // pos_emb staging; hid32 in E1
  __shared__ __align__(16) float v_s[NN][UPAD];
  __shared__ __align__(16) unsigned short hfH[8][64][8],  hfL[8][64][8];   // h A-frags (16 KB)
  __shared__ __align__(16) unsigned short agfH[8][64][8], agfL[8][64][8];  // aggr A-frags; hid frags in E2
  __shared__ __align__(16) unsigned short w2fH[8][4][64][8], w2fL[8][4][64][8]; // W2 B-frags (64 KB)
  __shared__ float e_s[EMB];
  __shared__ float c5_s[EMB];
  __shared__ float b2m_s[EMB];
  __shared__ float clsU[2][EMB], clsV[2][EMB];
  __shared__ float enc_s[ENCD];
  __shared__ float hidA_s[64];
  __shared__ float posx_s[NN], posy_s[NN];
  __shared__ int   T_s[NN];

  const int b    = blockIdx.x;
  const int tid  = threadIdx.x;
  const int w    = tid >> 6, lane = tid & 63;   // 8 waves
  const int o    = tid & 127, g = tid >> 7;     // node-group mapping for VALU phases
  const int l15  = lane & 15, l4 = lane >> 4;

  // ---------------- Phase A: decoder_fc -> e_s ----------------
  if (tid < ENCD) enc_s[tid] = enc[b * ENCD + tid];
  if (tid < NN) {
    posx_s[tid] = pos[(b * NN + tid) * 2 + 0];
    posy_s[tid] = pos[(b * NN + tid) * 2 + 1];
    T_s[tid]    = T[b * NN + tid];
  }
  __syncthreads();
  if (tid < 64) {
    float a = fc1_b[tid];
    const float* wr = fc1_w + tid * ENCD;
    #pragma unroll 8
    for (int k = 0; k < ENCD; k++) a += enc_s[k] * wr[k];
    hidA_s[tid] = fast_tanh(a);
  }
  __syncthreads();
  if (tid < EMB) {
    float a = fc2_b[tid];
    const float* wr = fc2_w + tid * 64;
    #pragma unroll 8
    for (int k = 0; k < 64; k++) a += hidA_s[k] * wr[k];
    e_s[tid] = a;
  }
  float* pe_s = &u_s[0][0];
  for (int idx = tid; idx < NN * PEMB; idx += 512)
    pe_s[idx] = pos_emb[b * NN * PEMB + idx];
  __syncthreads();

  // ---------------- Phase B: h0 = x @ lin_w^T + lin_b ----------------
  {
    const float nav = na_emb[b];
    const float* wr = lin_w + o * IND;
    float ebias = lin_b[o] + nav * wr[PEMB];
    #pragma unroll 8
    for (int k = 0; k < EMB; k++) ebias += e_s[k] * wr[65 + k];
    float acc[8];
    #pragma unroll
    for (int n = 0; n < 8; n++) acc[n] = ebias;
    for (int kc = 0; kc < PEMB; kc += 16) {
      float wreg[16];
      #pragma unroll
      for (int q = 0; q < 16; q++) wreg[q] = wr[kc + q];
      #pragma unroll
      for (int n = 0; n < 8; n++)
        acc[n] += dot16_lds(&pe_s[(g + 4 * n) * PEMB + kc], wreg);
    }
    __syncthreads();   // pe reads done before u_s reuse
    #pragma unroll
    for (int n = 0; n < 8; n++) h32[g + 4 * n][o] = acc[n];
  }
  __syncthreads();
  cvt_plane(h32, hfH, hfL, w, lane);
  __syncthreads();

  // ---------------- Layer loop ----------------
  for (int l = 0; l < NLAY; l++) {
    const float* b1  = msg_b1 + l * EMB;
    const float* b2  = msg_b2 + l * EMB;
    const float* ub1 = upd_b1 + l * EMB;
    const float* ub2 = upd_b2 + l * EMB;
    const float* w1  = msg_w1 + l * EMB * W1C;   // c5/cls columns only

    // ---- stage: c5, b2, cls tables; W2 frags -> LDS ----
    if (tid < EMB) { c5_s[tid] = w1[tid * W1C + 260]; b2m_s[tid] = b2[tid]; }
    {
      const int c = (tid >> 7) & 1, oo = tid & 127;
      if (tid < 256) clsU[c][oo] = b1[oo] + w1[oo * W1C + 258 + c];
      else           clsV[c][oo] = w1[oo * W1C + 256 + c];
    }
    {
      const unsigned short* sH = g_wD_h + l * 16384;
      const unsigned short* sL = g_wD_l + l * 16384;
      unsigned short* dH = &w2fH[0][0][0][0];
      unsigned short* dL = &w2fL[0][0][0][0];
      for (int idx = tid; idx < 2048; idx += 512) {
        *(short8*)(dH + idx * 8) = *(const short8*)(sH + idx * 8);
        *(short8*)(dL + idx * 8) = *(const short8*)(sL + idx * 8);
      }
    }
    __syncthreads();   // (1) tables + w2f ready, h-frags ready

    // ---- Phase C: u,v = h @ W1parts^T via MFMA; B-frags from g_wC ----
    {
      #pragma unroll
      for (int tt = 0; tt < 2; tt++) {
        const int tile = 2 * w + tt;
        const int part = tile >> 3;
        const int col  = ((tile & 7) << 4) + l15;
        floatx4 acc0 = {0.f,0.f,0.f,0.f}, acc1 = {0.f,0.f,0.f,0.f};
        #pragma unroll
        for (int ks = 0; ks < 4; ks++) {
          const int idx = (((l * 16 + tile) * 4 + ks) * 64 + lane) * 8;
          const short8 bh = *(const short8*)(g_wC_h + idx);
          const short8 bl = *(const short8*)(g_wC_l + idx);
          const short8 ah0 = *(const short8*)&hfH[ks*2+0][lane][0];
          const short8 al0 = *(const short8*)&hfL[ks*2+0][lane][0];
          const short8 ah1 = *(const short8*)&hfH[ks*2+1][lane][0];
          const short8 al1 = *(const short8*)&hfL[ks*2+1][lane][0];
          acc0 = mfma3(ah0, al0, bh, bl, acc0);
          acc1 = mfma3(ah1, al1, bh, bl, acc1);
        }
        float (*dst)[UPAD] = part ? v_s : u_s;
        const float (*tab)[EMB] = part ? clsV : clsU;
        #pragma unroll
        for (int q = 0; q < 4; q++) {
          const int r0 = (l4 << 2) + q;
          const int r1 = r0 + 16;
          dst[r0][col] = acc0[q] + tab[T_s[r0]][col];
          dst[r1][col] = acc1[q] + tab[T_s[r1]][col];
        }
      }
    }
    __syncthreads();   // (2) u,v ready

    // ---- Phase D: wave-independent. Wave w owns dst nodes i = 4w..4w+3.
    //      t(i) A-frags built entirely in registers; B from w2f LDS;
    //      aggr scattered directly into agf (bf16 hi/lo frag layout). ----
    {
      const int j0 = l15;          // rows for even planes (jt=0)
      const int j1 = l15 + 16;     // rows for odd planes  (jt=1)
      const float pj0x = posx_s[j0], pj0y = posy_s[j0];
      const float pj1x = posx_s[j1], pj1y = posy_s[j1];
      for (int ii = 0; ii < 4; ii++) {
        const int i = (w << 2) + ii;
        const float pix = posx_s[i], piy = posy_s[i];
        const float dx0 = pj0x - pix, dy0 = pj0y - piy;
        const float dx1 = pj1x - pix, dy1 = pj1y - piy;
        const float d0 = sqrtf(dx0 * dx0 + dy0 * dy0);
        const float d1 = sqrtf(dx1 * dx1 + dy1 * dy1);
        // build 8 A-frag planes in registers
        short8 aF[8];
        #pragma unroll
        for (int q = 0; q < 4; q++) {           // k-range q*32 + l4*8
          const int k8 = (q << 5) + (l4 << 3);
          float uv[8], v0[8], v1[8], c5q[8];
          *(float4*)&uv[0] = *(const float4*)&u_s[i][k8];
          *(float4*)&uv[4] = *(const float4*)&u_s[i][k8 + 4];
          *(float4*)&v0[0] = *(const float4*)&v_s[j0][k8];
          *(float4*)&v0[4] = *(const float4*)&v_s[j0][k8 + 4];
          *(float4*)&v1[0] = *(const float4*)&v_s[j1][k8];
          *(float4*)&v1[4] = *(const float4*)&v_s[j1][k8 + 4];
          *(float4*)&c5q[0] = *(const float4*)&c5_s[k8];
          *(float4*)&c5q[4] = *(const float4*)&c5_s[k8 + 4];
          float t0[8], t1[8];
          #pragma unroll
          for (int m = 0; m < 8; m++) {
            t0[m] = fast_tanh(uv[m] + v0[m] + d0 * c5q[m]);
            t1[m] = fast_tanh(uv[m] + v1[m] + d1 * c5q[m]);
          }
          uint4 p0 = make_uint4(cvtpk(t0[0], t0[1]), cvtpk(t0[2], t0[3]),
                                cvtpk(t0[4], t0[5]), cvtpk(t0[6], t0[7]));
          uint4 p1 = make_uint4(cvtpk(t1[0], t1[1]), cvtpk(t1[2], t1[3]),
                                cvtpk(t1[4], t1[5]), cvtpk(t1[6], t1[7]));
          aF[2 * q]     = *(short8*)&p0;
          aF[2 * q + 1] = *(short8*)&p1;
        }
        // all 8 col-tiles of W2
        #pragma unroll
        for (int ct = 0; ct < 8; ct++) {
          floatx4 a0 = {0.f,0.f,0.f,0.f}, a1 = {0.f,0.f,0.f,0.f};
          #pragma unroll
          for (int ks = 0; ks < 4; ks++) {
            const short8 bh = *(const short8*)&w2fH[ct][ks][lane][0];
            const short8 bl = *(const short8*)&w2fL[ct][ks][lane][0];
            a0 = __builtin_amdgcn_mfma_f32_16x16x32_bf16(aF[2*ks],   bl, a0, 0, 0, 0);
            a0 = __builtin_amdgcn_mfma_f32_16x16x32_bf16(aF[2*ks],   bh, a0, 0, 0, 0);
            a1 = __builtin_amdgcn_mfma_f32_16x16x32_bf16(aF[2*ks+1], bl, a1, 0, 0, 0);
            a1 = __builtin_amdgcn_mfma_f32_16x16x32_bf16(aF[2*ks+1], bh, a1, 0, 0, 0);
          }
          const float b2c = b2m_s[(ct << 4) + l15];
          float p = 0.f;
          #pragma unroll
          for (int q = 0; q < 4; q++)
            p += fast_tanh(a0[q] + b2c) + fast_tanh(a1[q] + b2c);
          p += __shfl_xor(p, 16);
          p += __shfl_xor(p, 32);
          if (lane < 16) {
            const int c     = (ct << 4) + l15;
            const int plane = ((c >> 5) << 1) + (i >> 4);
            const int slot  = (i & 15) + (((c >> 3) & 3) << 4);
            const int elem  = c & 7;
            const unsigned short hb = f2bf(p);
            agfH[plane][slot][elem] = hb;
            agfL[plane][slot][elem] = f2bf(p - bf2f(hb));
          }
        }
      }
    }
    __syncthreads();   // (3) agf complete; u_s free

    // ---- Phase E1: hid = tanh([h|aggr] @ uw1^T + ub1) -> u_s ----
    {
      const int col = (w << 4) + l15;
      const float bo = ub1[col];
      floatx4 acc0 = {0.f,0.f,0.f,0.f}, acc1 = {0.f,0.f,0.f,0.f};
      #pragma unroll
      for (int ks = 0; ks < 8; ks++) {
        const int idx = (((l * 8 + w) * 8 + ks) * 64 + lane) * 8;
        const short8 bh = *(const short8*)(g_wE1_h + idx);
        const short8 bl = *(const short8*)(g_wE1_l + idx);
        short8 ah0, al0, ah1, al1;
        if (ks < 4) {
          ah0 = *(const short8*)&hfH[ks*2+0][lane][0];  al0 = *(const short8*)&hfL[ks*2+0][lane][0];
          ah1 = *(const short8*)&hfH[ks*2+1][lane][0];  al1 = *(const short8*)&hfL[ks*2+1][lane][0];
        } else {
          ah0 = *(const short8*)&agfH[(ks-4)*2+0][lane][0];  al0 = *(const short8*)&agfL[(ks-4)*2+0][lane][0];
          ah1 = *(const short8*)&agfH[(ks-4)*2+1][lane][0];  al1 = *(const short8*)&agfL[(ks-4)*2+1][lane][0];
        }
        acc0 = mfma3(ah0, al0, bh, bl, acc0);
        acc1 = mfma3(ah1, al1, bh, bl, acc1);
      }
      __syncthreads();   // (4) agf/hf reads done before agf reuse as hid frags
      #pragma unroll
      for (int q = 0; q < 4; q++) {
        const int r0 = (l4 << 2) + q, r1 = r0 + 16;
        u_s[r0][col] = fast_tanh(acc0[q] + bo);   // u_s reused as hid32
        u_s[r1][col] = fast_tanh(acc1[q] + bo);
      }
    }
    __syncthreads();   // (5) hid32 ready

    cvt_plane(u_s, agfH, agfL, w, lane);   // hid frags into agf
    __syncthreads();   // (6)

    // ---- Phase E2: h += tanh(hid @ uw2^T + ub2) ----
    {
      const int col = (w << 4) + l15;
      const float bo = ub2[col];
      floatx4 acc0 = {0.f,0.f,0.f,0.f}, acc1 = {0.f,0.f,0.f,0.f};
      #pragma unroll
      for (int ks = 0; ks < 4; ks++) {
        const int idx = (((l * 8 + w) * 4 + ks) * 64 + lane) * 8;
        const short8 bh = *(const short8*)(g_wE2_h + idx);
        const short8 bl = *(const short8*)(g_wE2_l + idx);
        const short8 ah0 = *(const short8*)&agfH[ks*2+0][lane][0];
        const short8 al0 = *(const short8*)&agfL[ks*2+0][lane][0];
        const short8 ah1 = *(const short8*)&agfH[ks*2+1][lane][0];
        const short8 al1 = *(const short8*)&agfL[ks*2+1][lane][0];
        acc0 = mfma3(ah0, al0, bh, bl, acc0);
        acc1 = mfma3(ah1, al1, bh, bl, acc1);
      }
      #pragma unroll
      for (int q = 0; q < 4; q++) {
        const int r0 = (l4 << 2) + q, r1 = r0 + 16;
        h32[r0][col] += fast_tanh(acc0[q] + bo);
        h32[r1][col] += fast_tanh(acc1[q] + bo);
      }
    }
    __syncthreads();   // (7) h updated

    if (l + 1 < NLAY) {
      cvt_plane(h32, hfH, hfL, w, lane);
      __syncthreads();
    }
  }

  // ---------------- write out ----------------
  for (int idx = tid; idx < NN * EMB; idx += 512)
    out[b * NN * EMB + idx] = h32[idx >> 7][idx & 127];
}

extern "C" void kernel_launch(void* const* d_in, const int* in_sizes, int n_in,
                              void* d_out, int out_size, void* d_ws, size_t ws_size,
                              hipStream_t stream) {
  const float* pos     = (const float*)d_in[0];
  const float* enc     = (const float*)d_in[1];
  const float* pos_emb = (const float*)d_in[2];
  const float* na_emb  = (const float*)d_in[3];
  const int*   T       = (const int*)d_in[4];
  // d_in[5] = num_agents (compile-time 32)
  const float* fc1_w = (const float*)d_in[6];
  const float* fc1_b = (const float*)d_in[7];
  const float* fc2_w = (const float*)d_in[8];
  const float* fc2_b = (const float*)d_in[9];
  const float* lin_w = (const float*)d_in[10];
  const float* lin_b = (const float*)d_in[11];
  const float* msg_w1 = (const float*)d_in[12];
  const float* msg_b1 = (const float*)d_in[13];
  const float* msg_w2 = (const float*)d_in[14];
  const float* msg_b2 = (const float*)d_in[15];
  const float* upd_w1 = (const float*)d_in[16];
  const float* upd_b1 = (const float*)d_in[17];
  const float* upd_w2 = (const float*)d_in[18];
  const float* upd_b2 = (const float*)d_in[19];

  wconv<<<192, 256, 0, stream>>>(msg_w1, msg_w2, upd_w1, upd_w2);
  fsd_fused<<<256, 512, 0, stream>>>(pos, enc, pos_emb, na_emb, T,
      fc1_w, fc1_b, fc2_w, fc2_b, lin_w, lin_b,
      msg_w1, msg_b1, msg_b2, upd_b1, upd_b2,
      (float*)d_out);
}